// Round 1
// baseline (255.274 us; speedup 1.0000x reference)
//
#include <hip/hip_runtime.h>
#include <cstdint>
#include <cstddef>

// NonLocalBlock3D: B=2, C=256, Ci=128, N=D*H*W=8192.
// Pipeline: k0 prep -> k1 projections -> k2 flash attention -> k3 wy GEMM+stats -> k4 BN+residual.

typedef unsigned short u16;
typedef __bf16 bf16x8 __attribute__((ext_vector_type(8)));
typedef float f32x4 __attribute__((ext_vector_type(4)));
typedef unsigned short u16x8 __attribute__((ext_vector_type(8)));

#define B_ 2
#define C_ 256
#define CI_ 128
#define N_ 8192

static __device__ __forceinline__ u16 f2bf(float f){
  unsigned u = __builtin_bit_cast(unsigned, f);
  unsigned r = (u + 0x7FFFu + ((u>>16)&1u)) >> 16;
  return (u16)r;
}
static __device__ __forceinline__ f32x4 f4zero(){
  f32x4 v; v[0]=0.f; v[1]=0.f; v[2]=0.f; v[3]=0.f; return v;
}
static __device__ __forceinline__ f32x4 mfma16(bf16x8 a, bf16x8 b, f32x4 c){
  return __builtin_amdgcn_mfma_f32_16x16x32_bf16(a, b, c, 0, 0, 0);
}

// ---------------- K0: weight pack (fp32 -> bf16), bias concat, zero stats ----------------
__global__ void k0_prep(const float* __restrict__ Wt, const float* __restrict__ Wp,
                        const float* __restrict__ Wg, const float* __restrict__ Ww,
                        const float* __restrict__ bt, const float* __restrict__ bp,
                        const float* __restrict__ bg,
                        u16* __restrict__ Wcat, u16* __restrict__ Wwb,
                        float* __restrict__ biasc, float* __restrict__ stats){
  int t = blockIdx.x*blockDim.x + threadIdx.x;
  int nthr = gridDim.x*blockDim.x;
  for (int i = t; i < 32768; i += nthr){
    Wcat[i]        = f2bf(Wt[i]);
    Wcat[32768+i]  = f2bf(Wp[i]);
    Wcat[65536+i]  = f2bf(Wg[i]);
    Wwb[i]         = f2bf(Ww[i]);
  }
  for (int i = t; i < 128; i += nthr){
    biasc[i] = bt[i]; biasc[128+i] = bp[i]; biasc[256+i] = bg[i];
  }
  for (int i = t; i < 512; i += nthr) stats[i] = 0.f;
}

// ---------------- K1: fused transpose + 3 projections ----------------
// theta[b][n][128], kproj[b][n][128] (= phi^T), gT[b][128][n], all bf16 with bias.
// Block: 64 n-rows of one batch. A tile [64 n][256 c] bf16 in LDS (row stride 264).
__global__ __launch_bounds__(256) void k1_proj(const float* __restrict__ x,
     const u16* __restrict__ Wcat, const float* __restrict__ biasc,
     u16* __restrict__ theta, u16* __restrict__ kproj, u16* __restrict__ gT){
  __shared__ u16 At[64*264];     // 33792 B
  __shared__ u16 Wt_[32*264];    // 16896 B
  __shared__ u16 gbuf[32*72];    //  4608 B
  int tid = threadIdx.x;
  int b  = blockIdx.x >> 7;
  int nb = (blockIdx.x & 127) * 64;
  int w = tid >> 6, lane = tid & 63;
  int l15 = lane & 15, kg = lane >> 4;

  // Stage A: thread handles 2 channel rows (c0,c0+1) x 32 n, packing transposed pairs.
  {
    int cp = tid & 127, nh = tid >> 7;
    int c0 = cp*2;
    const float* src0 = x + ((size_t)(b*C_ + c0))*N_ + nb + nh*32;
    const float* src1 = src0 + N_;
#pragma unroll
    for (int j=0;j<8;j++){
      f32x4 a = *(const f32x4*)(src0 + j*4);
      f32x4 c = *(const f32x4*)(src1 + j*4);
#pragma unroll
      for (int q=0;q<4;q++){
        unsigned pk = (unsigned)f2bf(a[q]) | ((unsigned)f2bf(c[q])<<16);
        *(unsigned*)&At[(nh*32 + j*4 + q)*264 + c0] = pk;
      }
    }
  }
  __syncthreads();

  // hoist A fragments (same for all output chunks)
  bf16x8 afr[8];
#pragma unroll
  for (int kc=0;kc<8;kc++)
    afr[kc] = *(const bf16x8*)&At[(w*16+l15)*264 + kc*32 + kg*8];

  for (int och = 0; och < 12; och++){
    // stage W chunk [32 o][256 c]
    {
      int o8 = tid>>3, cp8 = tid&7;
      const u16* wsrc = Wcat + ((size_t)(och*32 + o8))*256 + cp8*8;
#pragma unroll
      for (int j=0;j<4;j++)
        *(u16x8*)&Wt_[o8*264 + cp8*8 + j*64] = *(const u16x8*)(wsrc + j*64);
    }
    __syncthreads();

    f32x4 acc0 = f4zero(), acc1 = f4zero();
#pragma unroll
    for (int kc=0;kc<8;kc++){
      bf16x8 b0 = *(const bf16x8*)&Wt_[(l15)*264 + kc*32 + kg*8];
      bf16x8 b1 = *(const bf16x8*)&Wt_[(16+l15)*264 + kc*32 + kg*8];
      acc0 = mfma16(afr[kc], b0, acc0);
      acc1 = mfma16(afr[kc], b1, acc1);
    }

    if (och < 8){
      u16* dst = (och < 4) ? theta : kproj;
      int oo = (och & 3) * 32;
#pragma unroll
      for (int of=0;of<2;of++){
        int o = oo + of*16 + l15;
        float bias = biasc[och*32 + of*16 + l15];
        f32x4 acc = of ? acc1 : acc0;
#pragma unroll
        for (int i=0;i<4;i++){
          int n = nb + w*16 + kg*4 + i;
          dst[((size_t)b*N_ + n)*CI_ + o] = f2bf(acc[i] + bias);
        }
      }
      __syncthreads();   // Wt_ reads done before next stage
    } else {
      // g chunk: bounce through gbuf for coalesced transposed store
#pragma unroll
      for (int of=0;of<2;of++){
        int o = of*16 + l15;
        float bias = biasc[och*32 + of*16 + l15];
        f32x4 acc = of ? acc1 : acc0;
#pragma unroll
        for (int i=0;i<4;i++){
          int r = w*16 + kg*4 + i;
          gbuf[o*72 + r] = f2bf(acc[i] + bias);
        }
      }
      __syncthreads();
      {
        int o = tid>>3, np = tid&7;
        int og = (och-8)*32 + o;
        u16x8 v = *(const u16x8*)&gbuf[o*72 + np*8];
        *(u16x8*)(gT + ((size_t)b*CI_ + og)*N_ + nb + np*8) = v;
      }
      __syncthreads();
    }
  }
}

// ---------------- K2: flash attention ----------------
// Block: 64 q-rows (4 waves x 16 rows), loop over 128 KV tiles of 64.
// Kt[m][c] (stride 136 el), Vt[c][m] (stride 72 el) padded against bank conflicts.
// Double-buffered, reg-staged (T14: issue loads early, LDS-write after compute).
__global__ __launch_bounds__(256) void k2_attn(const u16* __restrict__ theta,
      const u16* __restrict__ kproj, const u16* __restrict__ gT,
      float* __restrict__ y){
  __shared__ u16 Kt[2][64*136];   // 2 x 17408 B
  __shared__ u16 Vt[2][128*72];   // 2 x 18432 B
  __shared__ u16 Pl[4][16*72];    // 4 x  2304 B (per-wave P tile)
  int tid = threadIdx.x;
  int b  = blockIdx.x >> 7;
  int qb = (blockIdx.x & 127) * 64;
  int w = tid>>6, lane = tid&63;
  int l15 = lane&15, kg = lane>>4;

  // Q fragments in registers
  bf16x8 qf[4];
  {
    const u16* qsrc = theta + ((size_t)b*N_ + qb + w*16 + l15)*CI_ + kg*8;
#pragma unroll
    for (int kc=0;kc<4;kc++) qf[kc] = *(const bf16x8*)(qsrc + kc*32);
  }

  // staging pointers (tile 0)
  int km = tid>>2, kcp = tid&3;
  const u16* ksrc0 = kproj + ((size_t)b*N_ + km)*CI_ + kcp*32;
  u16* kdst = &Kt[0][km*136 + kcp*32];
  int vc = tid>>1, vmp = tid&1;
  const u16* vsrc0 = gT + ((size_t)b*CI_ + vc)*N_ + vmp*32;
  u16* vdst = &Vt[0][vc*72 + vmp*32];

  f32x4 oacc[8];
#pragma unroll
  for (int i=0;i<8;i++) oacc[i] = f4zero();
  float mrun[4], lrun[4];
#pragma unroll
  for (int i=0;i<4;i++){ mrun[i] = -1e30f; lrun[i] = 0.f; }

  // prologue: stage tile 0 into buf0
#pragma unroll
  for (int j=0;j<4;j++) *(u16x8*)(kdst + j*8) = *(const u16x8*)(ksrc0 + j*8);
#pragma unroll
  for (int j=0;j<4;j++) *(u16x8*)(vdst + j*8) = *(const u16x8*)(vsrc0 + j*8);
  __syncthreads();

  const int NT = N_/64;
  for (int t=0; t<NT; t++){
    int cur = t & 1;
    u16x8 kst[4], vst[4];
    bool pf = (t+1 < NT);
    if (pf){
      const u16* ks = ksrc0 + (size_t)(t+1)*64*CI_;
      const u16* vs = vsrc0 + (t+1)*64;
#pragma unroll
      for (int j=0;j<4;j++) kst[j] = *(const u16x8*)(ks + j*8);
#pragma unroll
      for (int j=0;j<4;j++) vst[j] = *(const u16x8*)(vs + j*8);
    }

    // S = Q K^T  (16x64 per wave)
    f32x4 s[4];
#pragma unroll
    for (int mf=0;mf<4;mf++) s[mf] = f4zero();
#pragma unroll
    for (int kc=0;kc<4;kc++){
#pragma unroll
      for (int mf=0;mf<4;mf++){
        bf16x8 bfr = *(const bf16x8*)&Kt[cur][(mf*16+l15)*136 + kc*32 + kg*8];
        s[mf] = mfma16(qf[kc], bfr, s[mf]);
      }
    }

    // online softmax: row r = kg*4+i, cols across mf (in-lane) x 16 lanes (shfl group)
    float mnew[4], scale[4];
#pragma unroll
    for (int i=0;i<4;i++){
      float mx = fmaxf(fmaxf(s[0][i], s[1][i]), fmaxf(s[2][i], s[3][i]));
      mx = fmaxf(mx, __shfl_xor(mx, 1));
      mx = fmaxf(mx, __shfl_xor(mx, 2));
      mx = fmaxf(mx, __shfl_xor(mx, 4));
      mx = fmaxf(mx, __shfl_xor(mx, 8));
      mnew[i] = fmaxf(mrun[i], mx);
      scale[i] = __expf(mrun[i] - mnew[i]);
      mrun[i] = mnew[i];
    }
    float psum[4] = {0.f,0.f,0.f,0.f};
#pragma unroll
    for (int mf=0;mf<4;mf++){
#pragma unroll
      for (int i=0;i<4;i++){
        float p = __expf(s[mf][i] - mnew[i]);
        psum[i] += p;
        Pl[w][(kg*4 + i)*72 + mf*16 + l15] = f2bf(p);
      }
    }
#pragma unroll
    for (int i=0;i<4;i++){
      float ps = psum[i];
      ps += __shfl_xor(ps, 1); ps += __shfl_xor(ps, 2);
      ps += __shfl_xor(ps, 4); ps += __shfl_xor(ps, 8);
      lrun[i] = lrun[i]*scale[i] + ps;
    }
    // rescale O
#pragma unroll
    for (int cf=0;cf<8;cf++){
#pragma unroll
      for (int i=0;i<4;i++) oacc[cf][i] *= scale[i];
    }
    // O += P V
#pragma unroll
    for (int k2=0;k2<2;k2++){
      bf16x8 pa = *(const bf16x8*)&Pl[w][l15*72 + k2*32 + kg*8];
#pragma unroll
      for (int cf=0;cf<8;cf++){
        bf16x8 vb = *(const bf16x8*)&Vt[cur][(cf*16+l15)*72 + k2*32 + kg*8];
        oacc[cf] = mfma16(pa, vb, oacc[cf]);
      }
    }

    if (pf){
      u16* kd = kdst + (cur^1)*(64*136);
      u16* vd = vdst + (cur^1)*(128*72);
#pragma unroll
      for (int j=0;j<4;j++) *(u16x8*)(kd + j*8) = kst[j];
#pragma unroll
      for (int j=0;j<4;j++) *(u16x8*)(vd + j*8) = vst[j];
    }
    __syncthreads();
  }

  // epilogue: y[b][n][c] = O/l
  float inv[4];
#pragma unroll
  for (int i=0;i<4;i++) inv[i] = 1.f/lrun[i];
  float* ydst = y + ((size_t)b*N_ + qb + w*16)*CI_;
#pragma unroll
  for (int cf=0;cf<8;cf++){
#pragma unroll
    for (int i=0;i<4;i++)
      ydst[(kg*4+i)*CI_ + cf*16 + l15] = oacc[cf][i]*inv[i];
  }
}

// ---------------- K3: wy = Ww @ y + bw, plus per-channel sum/sumsq (atomics) ----------------
__global__ __launch_bounds__(256) void k3_wy(const float* __restrict__ y,
    const u16* __restrict__ Wwb, const float* __restrict__ bw,
    float* __restrict__ wy, float* __restrict__ stats){
  __shared__ u16 Yt[64*136];
  __shared__ u16 Wt_[64*136];
  __shared__ float wyb[64*72];
  int tid = threadIdx.x;
  int b  = blockIdx.x >> 7;
  int nb = (blockIdx.x & 127) * 64;
  int w = tid>>6, lane = tid&63;
  int l15 = lane&15, kg = lane>>4;

  // stage y tile [64 n][128 c] -> bf16
  {
    int n = tid>>2, cp = tid&3;
    const float* src = y + ((size_t)b*N_ + nb + n)*CI_ + cp*32;
#pragma unroll
    for (int j=0;j<8;j++){
      f32x4 v = *(const f32x4*)(src + j*4);
      unsigned p0 = (unsigned)f2bf(v[0]) | ((unsigned)f2bf(v[1])<<16);
      unsigned p1 = (unsigned)f2bf(v[2]) | ((unsigned)f2bf(v[3])<<16);
      *(unsigned*)&Yt[n*136 + cp*32 + j*4]     = p0;
      *(unsigned*)&Yt[n*136 + cp*32 + j*4 + 2] = p1;
    }
  }
  __syncthreads();

  bf16x8 afr[4];
#pragma unroll
  for (int kc=0;kc<4;kc++)
    afr[kc] = *(const bf16x8*)&Yt[(w*16+l15)*136 + kc*32 + kg*8];

  for (int oc=0; oc<4; oc++){
    {
      int o = tid>>2, cp = tid&3;
      const u16* src = Wwb + ((size_t)(oc*64 + o))*CI_ + cp*32;
#pragma unroll
      for (int j=0;j<4;j++)
        *(u16x8*)&Wt_[o*136 + cp*32 + j*8] = *(const u16x8*)(src + j*8);
    }
    __syncthreads();

    f32x4 acc[4];
#pragma unroll
    for (int of=0;of<4;of++) acc[of] = f4zero();
#pragma unroll
    for (int kc=0;kc<4;kc++){
#pragma unroll
      for (int of=0;of<4;of++){
        bf16x8 bfr = *(const bf16x8*)&Wt_[(of*16+l15)*136 + kc*32 + kg*8];
        acc[of] = mfma16(afr[kc], bfr, acc[of]);
      }
    }
    // bounce to wyb[o][n]
#pragma unroll
    for (int of=0;of<4;of++){
#pragma unroll
      for (int i=0;i<4;i++)
        wyb[(of*16+l15)*72 + w*16 + kg*4 + i] = acc[of][i];
    }
    __syncthreads();
    // write wy (coalesced) + stats
    {
      int o = tid>>2, np = tid&3;
      int og = oc*64 + o;
      float bias = bw[og];
      float sm = 0.f, sq = 0.f;
      float* dst = wy + ((size_t)b*C_ + og)*N_ + nb + np*16;
#pragma unroll
      for (int j=0;j<4;j++){
        f32x4 v;
#pragma unroll
        for (int q=0;q<4;q++){
          float t2 = wyb[o*72 + np*16 + j*4 + q] + bias;
          v[q] = t2; sm += t2; sq += t2*t2;
        }
        *(f32x4*)(dst + j*4) = v;
      }
      sm += __shfl_xor(sm, 1); sm += __shfl_xor(sm, 2);
      sq += __shfl_xor(sq, 1); sq += __shfl_xor(sq, 2);
      if ((tid&3)==0){
        atomicAdd(&stats[og], sm);
        atomicAdd(&stats[256+og], sq);
      }
    }
    __syncthreads();
  }
}

// ---------------- K4: BN (training-mode batch stats) + residual ----------------
__global__ __launch_bounds__(256) void k4_bn(const float* __restrict__ wy,
    const float* __restrict__ x, const float* __restrict__ stats,
    const float* __restrict__ gamma, const float* __restrict__ beta,
    float* __restrict__ out){
  size_t base = ((size_t)blockIdx.x)*2048 + (size_t)threadIdx.x*8;
  int o = (int)((base >> 13) & 255);
  const float invn = 1.f/16384.f;
  float mean = stats[o]*invn;
  float var  = stats[256+o]*invn - mean*mean;
  float rs = rsqrtf(var + 1e-5f);
  float g = gamma[o]*rs;
  float bb = beta[o];
  f32x4 a0 = *(const f32x4*)(wy + base);
  f32x4 a1 = *(const f32x4*)(wy + base + 4);
  f32x4 x0 = *(const f32x4*)(x + base);
  f32x4 x1 = *(const f32x4*)(x + base + 4);
  f32x4 r0, r1;
#pragma unroll
  for (int q=0;q<4;q++){
    r0[q] = (a0[q]-mean)*g + bb + x0[q];
    r1[q] = (a1[q]-mean)*g + bb + x1[q];
  }
  *(f32x4*)(out + base)     = r0;
  *(f32x4*)(out + base + 4) = r1;
}

extern "C" void kernel_launch(void* const* d_in, const int* in_sizes, int n_in,
                              void* d_out, int out_size, void* d_ws, size_t ws_size,
                              hipStream_t stream){
  const float* x     = (const float*)d_in[0];
  const float* Wt    = (const float*)d_in[1];
  const float* bt    = (const float*)d_in[2];
  const float* Wp    = (const float*)d_in[3];
  const float* bp    = (const float*)d_in[4];
  const float* Wg    = (const float*)d_in[5];
  const float* bg    = (const float*)d_in[6];
  const float* Ww    = (const float*)d_in[7];
  const float* bw    = (const float*)d_in[8];
  const float* gamma = (const float*)d_in[9];
  const float* beta  = (const float*)d_in[10];

  char* ws = (char*)d_ws;
  u16*   theta = (u16*)(ws + 0);            // 4 MB  bf16 [2][8192][128]
  u16*   kproj = (u16*)(ws + 4194304);      // 4 MB  bf16 [2][8192][128]
  u16*   gT    = (u16*)(ws + 8388608);      // 4 MB  bf16 [2][128][8192]
  float* y     = (float*)(ws + 12582912);   // 8 MB  f32  [2][8192][128]
  float* wy    = (float*)(ws + 20971520);   // 16 MB f32  [2][256][8192]
  u16*   Wcat  = (u16*)(ws + 37748736);     // 192 KB bf16 [384][256]
  u16*   Wwb   = (u16*)(ws + 37945344);     // 64 KB  bf16 [256][128]
  float* biasc = (float*)(ws + 38010880);   // 1.5 KB
  float* stats = (float*)(ws + 38012416);   // 2 KB (sum[256], sumsq[256])
  float* out   = (float*)d_out;

  k0_prep<<<64, 256, 0, stream>>>(Wt, Wp, Wg, Ww, bt, bp, bg, Wcat, Wwb, biasc, stats);
  k1_proj<<<256, 256, 0, stream>>>(x, Wcat, biasc, theta, kproj, gT);
  k2_attn<<<256, 256, 0, stream>>>(theta, kproj, gT, y);
  k3_wy<<<256, 256, 0, stream>>>(y, Wwb, bw, wy, stats);
  k4_bn<<<2048, 256, 0, stream>>>(wy, x, stats, gamma, beta, out);
}

// Round 2
// 144.203 us; speedup vs baseline: 1.7702x; 1.7702x over previous
//
#include <hip/hip_runtime.h>
#include <cstdint>
#include <cstddef>

// NonLocalBlock3D: B=2, C=256, Ci=128, N=D*H*W=8192.
// k0 prep -> k1 projections -> k2 flash attention (KV-split, 32x32 swapped MFMA)
// -> k2b combine -> k3 wy GEMM+stats -> k4 BN+residual.

typedef unsigned short u16;
typedef __bf16 bf16x8 __attribute__((ext_vector_type(8)));
typedef float f32x4 __attribute__((ext_vector_type(4)));
typedef float f32x16 __attribute__((ext_vector_type(16)));
typedef unsigned short u16x8 __attribute__((ext_vector_type(8)));

#define B_ 2
#define C_ 256
#define CI_ 128
#define N_ 8192
#define CHUNKS 4
#define CHUNK_N 2048
#define KVB 64
#define NT (CHUNK_N/KVB)

static __device__ __forceinline__ u16 f2bf(float f){
  unsigned u = __builtin_bit_cast(unsigned, f);
  unsigned r = (u + 0x7FFFu + ((u>>16)&1u)) >> 16;
  return (u16)r;
}
static __device__ __forceinline__ float bf2f(u16 v){
  unsigned u = ((unsigned)v) << 16;
  return __builtin_bit_cast(float, u);
}
static __device__ __forceinline__ f32x4 f4zero(){
  f32x4 v; v[0]=0.f; v[1]=0.f; v[2]=0.f; v[3]=0.f; return v;
}
static __device__ __forceinline__ f32x16 f16zero(){
  f32x16 v;
#pragma unroll
  for (int i=0;i<16;i++) v[i]=0.f;
  return v;
}
static __device__ __forceinline__ f32x4 mfma16(bf16x8 a, bf16x8 b, f32x4 c){
  return __builtin_amdgcn_mfma_f32_16x16x32_bf16(a, b, c, 0, 0, 0);
}
static __device__ __forceinline__ f32x16 mfma32(bf16x8 a, bf16x8 b, f32x16 c){
  return __builtin_amdgcn_mfma_f32_32x32x16_bf16(a, b, c, 0, 0, 0);
}
static __device__ __forceinline__ unsigned cvtpk(float lo, float hi){
  unsigned r;
  asm("v_cvt_pk_bf16_f32 %0, %1, %2" : "=v"(r) : "v"(lo), "v"(hi));
  return r;
}
static __device__ __forceinline__ void plswap(unsigned &a, unsigned &b){
  asm volatile("v_permlane32_swap_b32 %0, %1" : "+v"(a), "+v"(b));
}

// ---------------- K0: weight pack (fp32 -> bf16), bias concat, zero stats ----------------
__global__ void k0_prep(const float* __restrict__ Wt, const float* __restrict__ Wp,
                        const float* __restrict__ Wg, const float* __restrict__ Ww,
                        const float* __restrict__ bt, const float* __restrict__ bp,
                        const float* __restrict__ bg,
                        u16* __restrict__ Wcat, u16* __restrict__ Wwb,
                        float* __restrict__ biasc, float* __restrict__ stats){
  int t = blockIdx.x*blockDim.x + threadIdx.x;
  int nthr = gridDim.x*blockDim.x;
  for (int i = t; i < 32768; i += nthr){
    Wcat[i]        = f2bf(Wt[i]);
    Wcat[32768+i]  = f2bf(Wp[i]);
    Wcat[65536+i]  = f2bf(Wg[i]);
    Wwb[i]         = f2bf(Ww[i]);
  }
  for (int i = t; i < 128; i += nthr){
    biasc[i] = bt[i]; biasc[128+i] = bp[i]; biasc[256+i] = bg[i];
  }
  for (int i = t; i < 512; i += nthr) stats[i] = 0.f;
}

// ---------------- K1: fused transpose + 3 projections ----------------
__global__ __launch_bounds__(256) void k1_proj(const float* __restrict__ x,
     const u16* __restrict__ Wcat, const float* __restrict__ biasc,
     u16* __restrict__ theta, u16* __restrict__ kproj, u16* __restrict__ gT){
  __shared__ u16 At[64*264];
  __shared__ u16 Wt_[32*264];
  __shared__ u16 gbuf[32*72];
  int tid = threadIdx.x;
  int b  = blockIdx.x >> 7;
  int nb = (blockIdx.x & 127) * 64;
  int w = tid >> 6, lane = tid & 63;
  int l15 = lane & 15, kg = lane >> 4;

  {
    int cp = tid & 127, nh = tid >> 7;
    int c0 = cp*2;
    const float* src0 = x + ((size_t)(b*C_ + c0))*N_ + nb + nh*32;
    const float* src1 = src0 + N_;
#pragma unroll
    for (int j=0;j<8;j++){
      f32x4 a = *(const f32x4*)(src0 + j*4);
      f32x4 c = *(const f32x4*)(src1 + j*4);
#pragma unroll
      for (int q=0;q<4;q++){
        unsigned pk = (unsigned)f2bf(a[q]) | ((unsigned)f2bf(c[q])<<16);
        *(unsigned*)&At[(nh*32 + j*4 + q)*264 + c0] = pk;
      }
    }
  }
  __syncthreads();

  bf16x8 afr[8];
#pragma unroll
  for (int kc=0;kc<8;kc++)
    afr[kc] = *(const bf16x8*)&At[(w*16+l15)*264 + kc*32 + kg*8];

  for (int och = 0; och < 12; och++){
    {
      int o8 = tid>>3, cp8 = tid&7;
      const u16* wsrc = Wcat + ((size_t)(och*32 + o8))*256 + cp8*8;
#pragma unroll
      for (int j=0;j<4;j++)
        *(u16x8*)&Wt_[o8*264 + cp8*8 + j*64] = *(const u16x8*)(wsrc + j*64);
    }
    __syncthreads();

    f32x4 acc0 = f4zero(), acc1 = f4zero();
#pragma unroll
    for (int kc=0;kc<8;kc++){
      bf16x8 b0 = *(const bf16x8*)&Wt_[(l15)*264 + kc*32 + kg*8];
      bf16x8 b1 = *(const bf16x8*)&Wt_[(16+l15)*264 + kc*32 + kg*8];
      acc0 = mfma16(afr[kc], b0, acc0);
      acc1 = mfma16(afr[kc], b1, acc1);
    }

    if (och < 8){
      u16* dst = (och < 4) ? theta : kproj;
      int oo = (och & 3) * 32;
#pragma unroll
      for (int of=0;of<2;of++){
        int o = oo + of*16 + l15;
        float bias = biasc[och*32 + of*16 + l15];
        f32x4 acc = of ? acc1 : acc0;
#pragma unroll
        for (int i=0;i<4;i++){
          int n = nb + w*16 + kg*4 + i;
          dst[((size_t)b*N_ + n)*CI_ + o] = f2bf(acc[i] + bias);
        }
      }
      __syncthreads();
    } else {
#pragma unroll
      for (int of=0;of<2;of++){
        int o = of*16 + l15;
        float bias = biasc[och*32 + of*16 + l15];
        f32x4 acc = of ? acc1 : acc0;
#pragma unroll
        for (int i=0;i<4;i++){
          int r = w*16 + kg*4 + i;
          gbuf[o*72 + r] = f2bf(acc[i] + bias);
        }
      }
      __syncthreads();
      {
        int o = tid>>3, np = tid&7;
        int og = (och-8)*32 + o;
        u16x8 v = *(const u16x8*)&gbuf[o*72 + np*8];
        *(u16x8*)(gT + ((size_t)b*CI_ + og)*N_ + nb + np*8) = v;
      }
      __syncthreads();
    }
  }
}

// ---------------- K2: flash attention, swapped 32x32 MFMA, KV-split ----------------
// Grid 256 blocks x 512 threads (8 waves x 32 q-rows). blockIdx&7 = (b,chunk) -> XCD.
// Kt [64 k][128 c] bf16 XOR-swizzled; Vt [128 c][64 k] bf16 XOR-swizzled; dbuf; 64 KB LDS.
__global__ __launch_bounds__(512, 2) void k2_attn(const u16* __restrict__ theta,
      const u16* __restrict__ kproj, const u16* __restrict__ gT,
      u16* __restrict__ pO, float* __restrict__ pM, float* __restrict__ pL){
  __shared__ char smem[65536];   // [0,32K): Kt dbuf, [32K,64K): Vt dbuf
  char* kbase = smem;
  char* vbase = smem + 32768;
  int tid = threadIdx.x;
  int bid = blockIdx.x;
  int combo = bid & 7;
  int b = combo & 1;
  int chunk = combo >> 1;
  int qblk = bid >> 3;                 // 0..31
  int n0 = chunk * CHUNK_N;
  int w = tid >> 6, lane = tid & 63;
  int l31 = lane & 31, hi = lane >> 5;
  int qg = qblk*256 + w*32 + l31;

  // Q into registers: lane holds its hi-half of row qg (64 of 128 channels)
  bf16x8 qf[8];
  {
    const u16* qsrc = theta + ((size_t)b*N_ + qg)*CI_ + hi*8;
#pragma unroll
    for (int cc=0; cc<8; cc++) qf[cc] = *(const bf16x8*)(qsrc + cc*16);
  }

  // staging assignment (512 threads, 32 B each per tile per array)
  int krow_s = tid >> 3, kpart = tid & 7;
  int vrow_s = tid >> 2, vpart = tid & 3;
  const u16* ksrc = kproj + ((size_t)b*N_ + n0 + krow_s)*CI_ + kpart*16;
  const u16* vsrc = gT + ((size_t)b*CI_ + vrow_s)*N_ + n0 + vpart*16;
  int kw_off[2], vw_off[2];
#pragma unroll
  for (int j=0;j<2;j++){
    int cb = kpart*32 + j*16;
    kw_off[j] = krow_s*256 + (cb ^ ((krow_s&7)<<4));
    int kb = vpart*32 + j*16;
    vw_off[j] = vrow_s*128 + (kb ^ ((vrow_s&7)<<4));
  }
  // precomputed read offsets (within one buffer)
  int swz = (l31&7)<<4;
  int kro[8], vro[4];
#pragma unroll
  for (int cc=0;cc<8;cc++) kro[cc] = l31*256 + ((cc*32 + hi*16) ^ swz);
#pragma unroll
  for (int ks=0;ks<4;ks++) vro[ks] = l31*128 + ((ks*32 + hi*16) ^ swz);

  // prologue: stage tile 0 into buf0
#pragma unroll
  for (int j=0;j<2;j++){
    *(u16x8*)(kbase + kw_off[j]) = *(const u16x8*)(ksrc + j*8);
    *(u16x8*)(vbase + vw_off[j]) = *(const u16x8*)(vsrc + j*8);
  }
  __syncthreads();

  f32x16 oacc[4];
#pragma unroll
  for (int i=0;i<4;i++) oacc[i] = f16zero();
  float mrun = -1e30f, lrun = 0.f;

  for (int t=0; t<NT; t++){
    int cur = t & 1;
    char* kb_c = kbase + cur*16384;
    char* vb_c = vbase + cur*16384;
    u16x8 kst[2], vst[2];
    bool pf = (t+1 < NT);
    if (pf){
      const u16* ks = ksrc + (size_t)(t+1)*KVB*CI_;
      const u16* vs = vsrc + (t+1)*KVB;
#pragma unroll
      for (int j=0;j<2;j++) kst[j] = *(const u16x8*)(ks + j*8);
#pragma unroll
      for (int j=0;j<2;j++) vst[j] = *(const u16x8*)(vs + j*8);
    }

    // --- QK^T (swapped): sA = S^T rows k 0..31, sB rows k 32..63; col = q = l31
    f32x16 sA = f16zero(), sB = f16zero();
    __builtin_amdgcn_s_setprio(1);
#pragma unroll
    for (int cc=0; cc<8; cc++){
      bf16x8 kf0 = *(const bf16x8*)(kb_c + kro[cc]);
      bf16x8 kf1 = *(const bf16x8*)(kb_c + 8192 + kro[cc]);
      sA = mfma32(kf0, qf[cc], sA);
      sB = mfma32(kf1, qf[cc], sB);
    }
    __builtin_amdgcn_s_setprio(0);

    // --- online softmax, fully in-register (lane owns q = l31; halves share via xor32)
    float t8[8];
#pragma unroll
    for (int i=0;i<8;i++) t8[i] = fmaxf(fmaxf(sA[i], sA[i+8]), fmaxf(sB[i], sB[i+8]));
    float m4a = fmaxf(t8[0], t8[4]), m4b = fmaxf(t8[1], t8[5]);
    float m4c = fmaxf(t8[2], t8[6]), m4d = fmaxf(t8[3], t8[7]);
    float mx = fmaxf(fmaxf(m4a, m4b), fmaxf(m4c, m4d));
    mx = fmaxf(mx, __shfl_xor(mx, 32));
    if (__any(mx > mrun + 8.f)){       // T13 defer-max
      float mnew = fmaxf(mrun, mx);
      float sc = __expf(mrun - mnew);
      lrun *= sc;
#pragma unroll
      for (int i=0;i<4;i++)
#pragma unroll
        for (int r=0;r<16;r++) oacc[i][r] *= sc;
      mrun = mnew;
    }
    float pA[16], pB[16];
#pragma unroll
    for (int r=0;r<16;r++){ pA[r] = __expf(sA[r]-mrun); pB[r] = __expf(sB[r]-mrun); }
    float s8[8];
#pragma unroll
    for (int i=0;i<8;i++) s8[i] = (pA[i]+pA[i+8]) + (pB[i]+pB[i+8]);
    float s4a = s8[0]+s8[4], s4b = s8[1]+s8[5], s4c = s8[2]+s8[6], s4d = s8[3]+s8[7];
    float ps = (s4a+s4b) + (s4c+s4d);
    ps += __shfl_xor(ps, 32);
    lrun += ps;

    // --- T14 write-late: staged regs -> other buffer (overlaps with PV)
    if (pf){
      char* kd = kbase + (cur^1)*16384;
      char* vd = vbase + (cur^1)*16384;
#pragma unroll
      for (int j=0;j<2;j++) *(u16x8*)(kd + kw_off[j]) = kst[j];
#pragma unroll
      for (int j=0;j<2;j++) *(u16x8*)(vd + vw_off[j]) = vst[j];
    }

    // --- PV (swapped): oacc[c2] = O^T chunk rows c, col q = l31
    __builtin_amdgcn_s_setprio(1);
#pragma unroll
    for (int ks=0; ks<4; ks++){
      const float* P = (ks<2) ? pA : pB;
      int r0 = (ks&1)*8;
      unsigned a0 = cvtpk(P[r0+0], P[r0+1]);
      unsigned b0 = cvtpk(P[r0+4], P[r0+5]);
      unsigned a1 = cvtpk(P[r0+2], P[r0+3]);
      unsigned b1 = cvtpk(P[r0+6], P[r0+7]);
      plswap(a0, b0); plswap(a1, b1);
      union { unsigned u[4]; bf16x8 v; } pb;
      pb.u[0]=a0; pb.u[1]=a1; pb.u[2]=b0; pb.u[3]=b1;
#pragma unroll
      for (int c2=0; c2<4; c2++){
        bf16x8 vf = *(const bf16x8*)(vb_c + c2*4096 + vro[ks]);
        oacc[c2] = mfma32(vf, pb.v, oacc[c2]);
      }
    }
    __builtin_amdgcn_s_setprio(0);
    __syncthreads();
  }

  // --- epilogue: O^T -> per-wave LDS region (bf16, swizzled) -> coalesced partial store
  char* region = smem + w*8192;   // 32 q x 128 c bf16 = 8 KB
#pragma unroll
  for (int c2=0;c2<4;c2++)
#pragma unroll
    for (int r=0;r<16;r++){
      int c = c2*32 + (r&3) + 8*(r>>2) + 4*hi;
      *(u16*)(region + l31*256 + ((c*2) ^ swz)) = f2bf(oacc[c2][r]);
    }
  __syncthreads();
  {
    int ql = lane >> 1, half = lane & 1;
    int qg2 = qblk*256 + w*32 + ql;
    u16* dst = pO + ((size_t)(chunk*2 + b)*N_ + qg2)*CI_ + half*64;
    int rswz = (ql&7)<<4;
#pragma unroll
    for (int j=0;j<8;j++){
      u16x8 v2 = *(const u16x8*)(region + ql*256 + ((half*128 + j*16) ^ rswz));
      *(u16x8*)(dst + j*8) = v2;
    }
  }
  if (hi == 0){
    pM[(size_t)(chunk*2 + b)*N_ + qg] = mrun;
    pL[(size_t)(chunk*2 + b)*N_ + qg] = lrun;
  }
}

// ---------------- K2b: combine KV-chunk partials -> y (f32) ----------------
__global__ __launch_bounds__(256) void k2b_combine(const u16* __restrict__ pO,
    const float* __restrict__ pM, const float* __restrict__ pL,
    float* __restrict__ y){
  int tid = threadIdx.x;
  int blk = blockIdx.x;                // 1024 blocks: b * 512 + qgroup
  int b = blk >> 9;
  int q = (blk & 511) * 16 + (tid >> 4);
  int c0 = (tid & 15) * 8;
  size_t qi = (size_t)b*N_ + q;
  float m0 = pM[qi], m1 = pM[2*(size_t)N_ + qi], m2 = pM[4*(size_t)N_ + qi], m3 = pM[6*(size_t)N_ + qi];
  float M = fmaxf(fmaxf(m0,m1), fmaxf(m2,m3));
  float w0 = __expf(m0-M), w1 = __expf(m1-M), w2 = __expf(m2-M), w3 = __expf(m3-M);
  float L = w0*pL[qi] + w1*pL[2*(size_t)N_+qi] + w2*pL[4*(size_t)N_+qi] + w3*pL[6*(size_t)N_+qi];
  float inv = 1.f/L;
  float wts[4] = {w0,w1,w2,w3};
  float acc[8];
#pragma unroll
  for (int i=0;i<8;i++) acc[i]=0.f;
  const u16* src = pO + qi*CI_ + c0;
#pragma unroll
  for (int ch=0; ch<4; ch++){
    u16x8 v = *(const u16x8*)(src + (size_t)ch*2*N_*CI_);
#pragma unroll
    for (int i=0;i<8;i++) acc[i] += wts[ch]*bf2f(v[i]);
  }
  float* dst = y + qi*CI_ + c0;
  f32x4 o0, o1;
#pragma unroll
  for (int i=0;i<4;i++){ o0[i] = acc[i]*inv; o1[i] = acc[4+i]*inv; }
  *(f32x4*)dst = o0;
  *(f32x4*)(dst+4) = o1;
}

// ---------------- K3: wy = Ww @ y + bw, plus per-channel sum/sumsq ----------------
__global__ __launch_bounds__(256) void k3_wy(const float* __restrict__ y,
    const u16* __restrict__ Wwb, const float* __restrict__ bw,
    float* __restrict__ wy, float* __restrict__ stats){
  __shared__ u16 Yt[64*136];
  __shared__ u16 Wt_[64*136];
  __shared__ float wyb[64*72];
  int tid = threadIdx.x;
  int b  = blockIdx.x >> 7;
  int nb = (blockIdx.x & 127) * 64;
  int w = tid>>6, lane = tid&63;
  int l15 = lane&15, kg = lane>>4;

  {
    int n = tid>>2, cp = tid&3;
    const float* src = y + ((size_t)b*N_ + nb + n)*CI_ + cp*32;
#pragma unroll
    for (int j=0;j<8;j++){
      f32x4 v = *(const f32x4*)(src + j*4);
      unsigned p0 = (unsigned)f2bf(v[0]) | ((unsigned)f2bf(v[1])<<16);
      unsigned p1 = (unsigned)f2bf(v[2]) | ((unsigned)f2bf(v[3])<<16);
      *(unsigned*)&Yt[n*136 + cp*32 + j*4]     = p0;
      *(unsigned*)&Yt[n*136 + cp*32 + j*4 + 2] = p1;
    }
  }
  __syncthreads();

  bf16x8 afr[4];
#pragma unroll
  for (int kc=0;kc<4;kc++)
    afr[kc] = *(const bf16x8*)&Yt[(w*16+l15)*136 + kc*32 + kg*8];

  for (int oc=0; oc<4; oc++){
    {
      int o = tid>>2, cp = tid&3;
      const u16* src = Wwb + ((size_t)(oc*64 + o))*CI_ + cp*32;
#pragma unroll
      for (int j=0;j<4;j++)
        *(u16x8*)&Wt_[o*136 + cp*32 + j*8] = *(const u16x8*)(src + j*8);
    }
    __syncthreads();

    f32x4 acc[4];
#pragma unroll
    for (int of=0;of<4;of++) acc[of] = f4zero();
#pragma unroll
    for (int kc=0;kc<4;kc++){
#pragma unroll
      for (int of=0;of<4;of++){
        bf16x8 bfr = *(const bf16x8*)&Wt_[(of*16+l15)*136 + kc*32 + kg*8];
        acc[of] = mfma16(afr[kc], bfr, acc[of]);
      }
    }
#pragma unroll
    for (int of=0;of<4;of++){
#pragma unroll
      for (int i=0;i<4;i++)
        wyb[(of*16+l15)*72 + w*16 + kg*4 + i] = acc[of][i];
    }
    __syncthreads();
    {
      int o = tid>>2, np = tid&3;
      int og = oc*64 + o;
      float bias = bw[og];
      float sm = 0.f, sq = 0.f;
      float* dst = wy + ((size_t)b*C_ + og)*N_ + nb + np*16;
#pragma unroll
      for (int j=0;j<4;j++){
        f32x4 v;
#pragma unroll
        for (int q=0;q<4;q++){
          float t2 = wyb[o*72 + np*16 + j*4 + q] + bias;
          v[q] = t2; sm += t2; sq += t2*t2;
        }
        *(f32x4*)(dst + j*4) = v;
      }
      sm += __shfl_xor(sm, 1); sm += __shfl_xor(sm, 2);
      sq += __shfl_xor(sq, 1); sq += __shfl_xor(sq, 2);
      if ((tid&3)==0){
        atomicAdd(&stats[og], sm);
        atomicAdd(&stats[256+og], sq);
      }
    }
    __syncthreads();
  }
}

// ---------------- K4: BN (batch stats) + residual ----------------
__global__ __launch_bounds__(256) void k4_bn(const float* __restrict__ wy,
    const float* __restrict__ x, const float* __restrict__ stats,
    const float* __restrict__ gamma, const float* __restrict__ beta,
    float* __restrict__ out){
  size_t base = ((size_t)blockIdx.x)*2048 + (size_t)threadIdx.x*8;
  int o = (int)((base >> 13) & 255);
  const float invn = 1.f/16384.f;
  float mean = stats[o]*invn;
  float var  = stats[256+o]*invn - mean*mean;
  float rs = rsqrtf(var + 1e-5f);
  float g = gamma[o]*rs;
  float bb = beta[o];
  f32x4 a0 = *(const f32x4*)(wy + base);
  f32x4 a1 = *(const f32x4*)(wy + base + 4);
  f32x4 x0 = *(const f32x4*)(x + base);
  f32x4 x1 = *(const f32x4*)(x + base + 4);
  f32x4 r0, r1;
#pragma unroll
  for (int q=0;q<4;q++){
    r0[q] = (a0[q]-mean)*g + bb + x0[q];
    r1[q] = (a1[q]-mean)*g + bb + x1[q];
  }
  *(f32x4*)(out + base)     = r0;
  *(f32x4*)(out + base + 4) = r1;
}

extern "C" void kernel_launch(void* const* d_in, const int* in_sizes, int n_in,
                              void* d_out, int out_size, void* d_ws, size_t ws_size,
                              hipStream_t stream){
  const float* x     = (const float*)d_in[0];
  const float* Wt    = (const float*)d_in[1];
  const float* bt    = (const float*)d_in[2];
  const float* Wp    = (const float*)d_in[3];
  const float* bp    = (const float*)d_in[4];
  const float* Wg    = (const float*)d_in[5];
  const float* bg    = (const float*)d_in[6];
  const float* Ww    = (const float*)d_in[7];
  const float* bw    = (const float*)d_in[8];
  const float* gamma = (const float*)d_in[9];
  const float* beta  = (const float*)d_in[10];

  char* ws = (char*)d_ws;
  // [0,4M): theta bf16 | [4M,8M): kproj bf16 | [8M,12M): gT bf16
  // [12M,28M): pO bf16 [4][2][8192][128]  (reused as wy f32 after k2b)
  // [28M,28M+256K): pM | +256K: pL | then packed weights
  u16*   theta = (u16*)(ws + 0);
  u16*   kproj = (u16*)(ws + 4194304);
  u16*   gT    = (u16*)(ws + 8388608);
  u16*   pO    = (u16*)(ws + 12582912);
  float* pM    = (float*)(ws + 29360128);
  float* pL    = (float*)(ws + 29622272);
  u16*   Wcat  = (u16*)(ws + 29884416);
  u16*   Wwb   = (u16*)(ws + 30081024);
  float* biasc = (float*)(ws + 30146560);
  float* stats = (float*)(ws + 30148096);
  float* y     = (float*)(ws + 0);          // aliases theta+kproj (dead after k2)
  float* wy    = (float*)(ws + 12582912);   // aliases pO (dead after k2b)
  float* out   = (float*)d_out;

  k0_prep<<<64, 256, 0, stream>>>(Wt, Wp, Wg, Ww, bt, bp, bg, Wcat, Wwb, biasc, stats);
  k1_proj<<<256, 256, 0, stream>>>(x, Wcat, biasc, theta, kproj, gT);
  k2_attn<<<256, 512, 0, stream>>>(theta, kproj, gT, pO, pM, pL);
  k2b_combine<<<1024, 256, 0, stream>>>(pO, pM, pL, y);
  k3_wy<<<256, 256, 0, stream>>>(y, Wwb, bw, wy, stats);
  k4_bn<<<2048, 256, 0, stream>>>(wy, x, stats, gamma, beta, out);
}